// Round 4
// baseline (609.157 us; speedup 1.0000x reference)
//
#include <hip/hip_runtime.h>
#include <hip/hip_bf16.h>
#include <math.h>

typedef __bf16 bf16x8 __attribute__((ext_vector_type(8)));
typedef float  f32x16 __attribute__((ext_vector_type(16)));

#define CI_STRIDE 262144   // 64*64*64
#define B_STRIDE  16777216 // 64*CI_STRIDE
#define Z2 68              // z' extent (64 + 2 halo each side)
#define CP 40              // padded ci-half leading dim (32 data + 8 pad; 80 B rows)
#define NROW 12            // 8 data y-rows + 2 halo each side

// ---------------------------------------------------------------------------
// Kernel 1: bf16 weights, layout Wb[t][h][co][ci32]  (h = ci-half).
// Folds 0.1 conv scale, ALPHA factors, cos(pi d)/5^1.5, sh1; center tap t=62
// absorbs the block-diagonal pointwise mix sc (0.25*lin_w).
// ---------------------------------------------------------------------------
__global__ __launch_bounds__(256) void gen_w(const float* __restrict__ tp,
                                             const float* __restrict__ lw0,
                                             const float* __restrict__ lw1,
                                             __bf16* __restrict__ Wb) {
    const int t  = blockIdx.x;            // tap id 0..124, t = dx*25+dy*5+dz
    const int dx = t / 25, dy = (t / 5) % 5, dz = t % 5;
    const float rx = -1.f + 0.5f * (float)dx;
    const float ry = -1.f + 0.5f * (float)dy;
    const float rz = -1.f + 0.5f * (float)dz;
    const float d    = sqrtf(rx * rx + ry * ry + rz * rz);
    const float invd = (d > 0.f) ? (1.f / d) : 0.f;
    const float SQRT3 = 1.7320508075688772f;
    const float sh1_0 = SQRT3 * ry * invd;   // sh1 = sqrt(3)*unit[[1,2,0]]
    const float sh1_1 = SQRT3 * rz * invd;
    const float sh1_2 = SQRT3 * rx * invd;
    float basis[5];
#pragma unroll
    for (int m = 0; m < 5; ++m) {
        float u = (d - 0.25f * (float)m) * 4.0f;
        basis[m] = expf(-u * u) * (1.0f / 1.12f);
    }
    const float S  = cosf(3.14159265358979323846f * d) * (1.0f / 11.180339887498949f);
    const float fA = 0.1f * 0.17677669529663687f * S;
    const float fB = 0.1f * 0.3061862178478972f * 0.5773502691896258f * S;
    const float fC = 0.1f * 0.17677669529663687f * 0.5773502691896258f * S;
    const float fD = fB;

    for (int e = threadIdx.x; e < 4096; e += 256) {
        const int co = e >> 6, ci = e & 63;
        int   tt;
        float f;
        if (ci < 16) {
            if (co < 16) { tt = ci * 16 + co; f = fA; }
            else {
                const int c = co - 16, w = c / 3, kk = c % 3;
                tt = 256 + ci * 16 + w;
                f  = fB * ((kk == 0) ? sh1_0 : (kk == 1) ? sh1_1 : sh1_2);
            }
        } else {
            const int a = ci - 16, uu = a / 3, ii = a % 3;
            const float s1i = (ii == 0) ? sh1_0 : (ii == 1) ? sh1_1 : sh1_2;
            if (co < 16) { tt = 768 + uu * 16 + co; f = fC * s1i; }
            else {
                const int c = co - 16, w = c / 3, kk = c % 3;
                tt = 512 + uu * 16 + w;
                f  = (ii == kk) ? fD : 0.0f;
            }
        }
        float E = 0.f;
#pragma unroll
        for (int m = 0; m < 5; ++m) E += basis[m] * tp[m * 1024 + tt];
        float val = f * E;
        if (t == 62) {  // fold sc into the center tap
            if (ci < 16 && co < 16) {
                val += 0.25f * lw0[ci * 16 + co];
            } else if (ci >= 16 && co >= 16) {
                const int a = co - 16, bq = ci - 16;
                const int wq = a / 3, iq = a % 3, uq = bq / 3, iiq = bq % 3;
                if (iq == iiq) val += 0.25f * lw1[uq * 16 + wq];
            }
        }
        // layout: Wb[((t*2 + h)*64 + co)*32 + ci_lo]
        Wb[((size_t)(t * 2 + (ci >> 5)) * 64 + co) * 32 + (ci & 31)] = (__bf16)val;
    }
}

// ---------------------------------------------------------------------------
// Kernel 2: implicit-GEMM conv, 32x32x16 MFMA. Block = 256 thr (4 waves).
// 65,280 B LDS -> 2 blocks/CU. Per tap per wave: M=64 co x N=128 (2y x 64z),
// K=32 -> 16 x mfma_f32_32x32x16_bf16 (2 am x 4 n-tiles x 2 k-slices).
// 32x32 pipe rate is ~13% better than 16x16 (2382 vs 2075 TF ubench) and
// halves MFMA issue slots. Per-tap serial section minimized: ping-pong named
// buffers (no register copies - r3's copies pushed VALUBusy 27->42% for no
// gain), incremental dy/dz (no div/mod), one base-VGPR per operand with all
// frag loads as compile-time immediate offsets.
// A-frag: lane&31 = co(row), k = ks*16 + (l>>5)*8 + j  (same family as the
// verified 16x16x32 mapping). B-frag: lane&31 = n(col), same k.
// C/D: col=lane&31, row=(reg&3)+8*(reg>>2)+4*(lane>>5)  [m74/m101 verified].
// ---------------------------------------------------------------------------
__global__ __launch_bounds__(256, 2) void conv_mfma(const float* __restrict__ x,
                                                    const __bf16* __restrict__ Wb,
                                                    float* __restrict__ out) {
    __shared__ __align__(16) __bf16 xs[NROW * Z2 * CP];   // 65,280 B
    const int tid = threadIdx.x;
    const int l = tid & 63, w = tid >> 6;     // 4 waves
    const int b  = blockIdx.x >> 9;
    const int xc = (blockIdx.x >> 3) & 63;
    const int y0 = (blockIdx.x & 7) << 3;

    f32x16 acc[2][4];
#pragma unroll
    for (int am = 0; am < 2; ++am)
#pragma unroll
        for (int nt = 0; nt < 4; ++nt) acc[am][nt] = (f32x16)(0.f);

    // zero the z-halo columns z' in {0,1,66,67}, ci 0..31 (staging never
    // writes them; values persist across all planes)
    if (tid < NROW * 4 * 4) {
        const int r = tid >> 4, rem = tid & 15;
        const int zs = rem >> 2, c8 = (rem & 3) << 3;
        const int zp = (zs < 2) ? zs : (64 + zs);
        bf16x8 zz = {(__bf16)0.f, (__bf16)0.f, (__bf16)0.f, (__bf16)0.f,
                     (__bf16)0.f, (__bf16)0.f, (__bf16)0.f, (__bf16)0.f};
        *(bf16x8*)(xs + ((size_t)r * Z2 + zp) * CP + c8) = zz;
    }

    const float* xb = x + (size_t)b * B_STRIDE;

    // hoisted per-lane address parts (elements)
    const int hi = l >> 5;                 // k-half selector
    const int l31 = l & 31;
    const int lane_lds = (2 * w * Z2 + l31) * CP + hi * 8;  // + tap*(...) scalar
    const int lane_a   = l31 * 32 + hi * 8;                 // within a 2048-elem tap block

    // frag loaders: all offsets compile-time -> 1 v_add + imm-offset loads/tap
    auto LOADB = [&](bf16x8* Bf, int tapoff) {
        const __bf16* bp = xs + lane_lds + tapoff;
#pragma unroll
        for (int ks = 0; ks < 2; ++ks)
#pragma unroll
            for (int nt = 0; nt < 4; ++nt)
                Bf[ks * 4 + nt] = *(const bf16x8*)(bp + (nt >> 1) * (Z2 * CP)
                                                    + (nt & 1) * (32 * CP) + ks * 16);
    };
    auto LOADA = [&](bf16x8* Af, const __bf16* wp) {
        const __bf16* ap = wp + lane_a;
#pragma unroll
        for (int am = 0; am < 2; ++am)
#pragma unroll
            for (int ks = 0; ks < 2; ++ks)
                Af[am * 2 + ks] = *(const bf16x8*)(ap + am * 1024 + ks * 16);
    };
    auto MSET = [&](const bf16x8* Af, const bf16x8* Bf) {
        __builtin_amdgcn_s_setprio(1);
#pragma unroll
        for (int ks = 0; ks < 2; ++ks)
#pragma unroll
            for (int am = 0; am < 2; ++am)
#pragma unroll
                for (int nt = 0; nt < 4; ++nt)
                    acc[am][nt] = __builtin_amdgcn_mfma_f32_32x32x16_bf16(
                        Af[am * 2 + ks], Bf[ks * 4 + nt], acc[am][nt], 0, 0, 0);
        __builtin_amdgcn_s_setprio(0);
    };

    for (int h = 0; h < 2; ++h) {
        for (int dx = 0; dx < 5; ++dx) {
            __syncthreads();   // all waves done reading the previous plane
            {   // stage plane x' = xc+dx-2, rows y' = y0-2 .. y0+9, ci-half h
                const int xp = xc + dx - 2;
                const bool xok = (xp >= 0) && (xp < 64);
                for (int r = w; r < NROW; r += 4) {
                    const int yp = y0 + r - 2;
                    const bool ok = xok && (yp >= 0) && (yp < 64);
                    const float* src = xb + (size_t)(h * 32) * CI_STRIDE
                                     + (size_t)xp * 4096 + yp * 64 + l;
                    __bf16* dst = xs + ((size_t)r * Z2 + 2 + l) * CP;
                    if (ok) {
#pragma unroll
                        for (int c0 = 0; c0 < 32; c0 += 8) {
                            bf16x8 pk;
#pragma unroll
                            for (int j = 0; j < 8; ++j)
                                pk[j] = (__bf16)src[(size_t)(c0 + j) * CI_STRIDE];
                            *(bf16x8*)(dst + c0) = pk;   // ds_write_b128
                        }
                    } else {
                        bf16x8 zz = {(__bf16)0.f, (__bf16)0.f, (__bf16)0.f, (__bf16)0.f,
                                     (__bf16)0.f, (__bf16)0.f, (__bf16)0.f, (__bf16)0.f};
#pragma unroll
                        for (int c0 = 0; c0 < 32; c0 += 8) *(bf16x8*)(dst + c0) = zz;
                    }
                }
            }
            __syncthreads();

            // 25 taps, 2x-unrolled ping-pong (no register copies)
            const __bf16* wplane = Wb + (size_t)((dx * 25) * 2 + h) * 2048;
            bf16x8 B0[8], B1[8], A0[4], A1[4];
            LOADB(B0, 0);
            LOADA(A0, wplane);
            int dyn = 0, dzn = 1;   // indices of the next tap to load
            for (int i = 0; i < 12; ++i) {
                LOADB(B1, (dyn * Z2 + dzn) * CP);
                LOADA(A1, wplane + (size_t)(2 * i + 1) * 4096);
                if (++dzn == 5) { dzn = 0; ++dyn; }
                MSET(A0, B0);                       // tap 2i
                LOADB(B0, (dyn * Z2 + dzn) * CP);
                LOADA(A0, wplane + (size_t)(2 * i + 2) * 4096);
                if (++dzn == 5) { dzn = 0; ++dyn; }
                MSET(A1, B1);                       // tap 2i+1
            }
            MSET(A0, B0);                           // tap 24
        }
    }

    // epilogue: C/D 32x32 layout: col=lane&31, row=(reg&3)+8*(reg>>2)+4*(l>>5)
    const size_t ob = (size_t)b * B_STRIDE + (size_t)xc * 4096;
#pragma unroll
    for (int am = 0; am < 2; ++am)
#pragma unroll
        for (int nt = 0; nt < 4; ++nt) {
            const int y = y0 + 2 * w + (nt >> 1);
            const int zb = (nt & 1) * 32 + l31;
            float* op = out + ob + (size_t)y * 64 + zb;
#pragma unroll
            for (int reg = 0; reg < 16; ++reg) {
                const int co = am * 32 + (reg & 3) + 8 * (reg >> 2) + 4 * hi;
                op[(size_t)co * CI_STRIDE] = acc[am][nt][reg];
            }
        }
}

extern "C" void kernel_launch(void* const* d_in, const int* in_sizes, int n_in,
                              void* d_out, int out_size, void* d_ws, size_t ws_size,
                              hipStream_t stream) {
    (void)in_sizes; (void)n_in; (void)out_size; (void)ws_size;
    const float* x   = (const float*)d_in[0];  // (2, 64, 64, 64, 64) fp32
    const float* lw0 = (const float*)d_in[1];  // (16, 16)
    const float* lw1 = (const float*)d_in[2];  // (16, 16)
    const float* tp  = (const float*)d_in[3];  // (5, 1024)
    float* out = (float*)d_out;
    __bf16* Wb = (__bf16*)d_ws;                // 125*2*64*32*2 B = 1.0 MB

    gen_w<<<125, 256, 0, stream>>>(tp, lw0, lw1, Wb);
    conv_mfma<<<1024, 256, 0, stream>>>(x, Wb, out);
}